// Round 7
// baseline (2155.424 us; speedup 1.0000x reference)
//
#include <hip/hip_runtime.h>
#include <math.h>

#define BB 64
#define SS 256
#define D_IN 400
#define D_RNN 200
#define HID 256
#define G4 1024   // 4*HID

// workspace layout (float offsets)
#define OFF_WTLIN 0                            // [400][200] f32
#define OFF_WTIH  (OFF_WTLIN + 400*200)        // [2][100][1024] u32 (f16 pairs)
#define OFF_WPACK (OFF_WTIH + 2*200*1024)      // [2][32 chunk][1024 row][8 f16]
#define OFF_X     (OFF_WPACK + 2*1024*256/2)   // [2][64][256][200] f32
#define OFF_GX    (OFF_X + 2*64*256*200)       // [2][64][256][1024] f32
// overlays inside xbuf region (xbuf dead once k_lstm runs; mail/flags written only by k_lstm)
#define OFF_MAIL  OFF_X                        // [128 seq][2 recv][2 parity][128 col][4] f32 = 262144 f
#define OFF_FLAG  (OFF_X + 400000)             // [256][32] u32 flag lines

typedef _Float16 half2_t __attribute__((ext_vector_type(2)));

__device__ __forceinline__ half2_t u2h(unsigned u) {
    union { unsigned u; half2_t h; } x; x.u = u; return x.h;
}

__device__ __forceinline__ float dot2acc(unsigned hu, unsigned wu, float acc) {
#if __has_builtin(__builtin_amdgcn_fdot2)
    return __builtin_amdgcn_fdot2(u2h(hu), u2h(wu), acc, false);
#else
    half2_t h = u2h(hu), w = u2h(wu);
    acc = fmaf((float)h.x, (float)w.x, acc);
    acc = fmaf((float)h.y, (float)w.y, acc);
    return acc;
#endif
}

__device__ __forceinline__ unsigned packf16(float a, float b) {
    union { _Float16 h[2]; unsigned u; } x;
    x.h[0] = (_Float16)a; x.h[1] = (_Float16)b;
    return x.u;
}

__device__ __forceinline__ float sigm_f(float x) {
    return 1.0f / (1.0f + __expf(-x));
}
__device__ __forceinline__ float tanh_f(float x) {
    return 2.0f / (1.0f + __expf(-2.0f * x)) - 1.0f;
}

// ---------------- transposes / packs ----------------
__global__ void kt_wlin(const float* __restrict__ W, float* __restrict__ Wt) {
    int id = blockIdx.x * 256 + threadIdx.x;
    if (id >= D_RNN * D_IN) return;
    int j = id / D_IN, k = id % D_IN;
    Wt[k * D_RNN + j] = W[id];
}

// Wih f32 [1024][200] -> f16-pair pack
__global__ void kt_wih16(const float* __restrict__ Wl, const float* __restrict__ Wr,
                         unsigned* __restrict__ Wt16) {
    int id = blockIdx.x * 256 + threadIdx.x;
    if (id >= 2 * G4 * 100) return;
    int dir = id / (G4 * 100);
    int rem = id % (G4 * 100);
    int j = rem / 100, kk = rem % 100;
    const float* src = dir ? Wr : Wl;
    Wt16[(dir * 100 + kk) * G4 + j] = packf16(src[j * D_RNN + 2 * kk],
                                              src[j * D_RNN + 2 * kk + 1]);
}

// Whh f32 [row][k] -> f16 packed chunk-major: wpack[dir][k/8][row][k%8]
__global__ void kt_wpack(const float* __restrict__ Wl, const float* __restrict__ Wr,
                         _Float16* __restrict__ Wp) {
    int id = blockIdx.x * 256 + threadIdx.x;
    if (id >= 2 * G4 * HID) return;
    int dir = id / (G4 * HID);
    int rem = id % (G4 * HID);
    int r = rem / HID, k = rem % HID;
    const float* src = dir ? Wr : Wl;
    Wp[(((size_t)dir * 32 + (k >> 3)) * G4 + r) * 8 + (k & 7)] = (_Float16)src[rem];
}

__global__ void kf_reset(unsigned* __restrict__ flags) {
    int id = blockIdx.x * 1024 + threadIdx.x;
    if (id < 256 * 32) flags[id] = 0u;
}

// ---------------- K1: embeddings + concat + linear + tanh ----------------
__launch_bounds__(512)
__global__ void k_embed_linear(const int* __restrict__ ci, const int* __restrict__ bli,
                               const int* __restrict__ bri, const int* __restrict__ sci,
                               const int* __restrict__ sbli, const int* __restrict__ sbri,
                               const float* __restrict__ ce, const float* __restrict__ be,
                               const float* __restrict__ sce, const float* __restrict__ sbe,
                               const float* __restrict__ Wt, const float* __restrict__ blin,
                               float* __restrict__ xout) {
    __shared__ __align__(16) float vec[16][2][D_IN];
    __shared__ int idx[16][6];
    int tid = threadIdx.x;
    int g0 = blockIdx.x * 16;

    if (tid < 96) {
        int tt = tid / 6, w = tid % 6;
        int g = g0 + tt;
        const int* arr = (w == 0) ? ci : (w == 1) ? sci : (w == 2) ? bli
                         : (w == 3) ? bri : (w == 4) ? sbli : sbri;
        idx[tt][w] = arr[g];
    }
    __syncthreads();

    for (int v = tid; v < 16 * D_IN; v += 512) {
        int tt = v / D_IN, p = v % D_IN;
        float lv, rv;
        if (p < 100)      { float e = ce[idx[tt][0] * 100 + p];          lv = rv = e; }
        else if (p < 200) { float e = sce[idx[tt][1] * 100 + (p - 100)]; lv = rv = e; }
        else if (p < 300) { int q = p - 200;
                            lv = be[idx[tt][2] * 100 + q];
                            rv = be[idx[tt][3] * 100 + q]; }
        else              { int q = p - 300;
                            lv = sbe[idx[tt][4] * 100 + q];
                            rv = sbe[idx[tt][5] * 100 + q]; }
        vec[tt][0][p] = lv;
        vec[tt][1][p] = rv;
    }
    __syncthreads();

    if (tid < 400) {
        int side = tid / 200, j = tid % 200;
        float acc[16];
        #pragma unroll
        for (int t = 0; t < 16; t++) acc[t] = 0.0f;

        for (int k4 = 0; k4 < D_IN / 4; k4++) {
            float w0 = Wt[(4 * k4 + 0) * D_RNN + j];
            float w1 = Wt[(4 * k4 + 1) * D_RNN + j];
            float w2 = Wt[(4 * k4 + 2) * D_RNN + j];
            float w3 = Wt[(4 * k4 + 3) * D_RNN + j];
            #pragma unroll
            for (int t = 0; t < 16; t++) {
                float4 xv = *(const float4*)&vec[t][side][4 * k4];
                acc[t] += xv.x * w0 + xv.y * w1 + xv.z * w2 + xv.w * w3;
            }
        }
        float bias = blin[j];
        #pragma unroll
        for (int t = 0; t < 16; t++) {
            int g = g0 + t;
            int b = g >> 8, s = g & 255;
            xout[((side * BB + b) * SS + s) * D_RNN + j] = tanh_f(acc[t] + bias);
        }
    }
}

// ---------------- K2: gate-x GEMM via f16 dot2 ----------------
__launch_bounds__(512)
__global__ void k_gatex(const float* __restrict__ x, const unsigned* __restrict__ Wt16,
                        const float* __restrict__ bihl, const float* __restrict__ bhhl,
                        const float* __restrict__ bihr, const float* __restrict__ bhhr,
                        float* __restrict__ gx) {
    __shared__ __align__(16) unsigned xT16[100][40];
    int tid = threadIdx.x;
    int id = blockIdx.x;
    int dir = id >> 9;
    int rem = id & 511;
    int b = rem >> 3;
    int s0 = (rem & 7) * 32;

    const float2* xb2 = reinterpret_cast<const float2*>(
        x + ((dir * BB + b) * SS + s0) * D_RNN);
    for (int v = tid; v < 32 * 100; v += 512) {
        int tok = v / 100, kk = v % 100;
        float2 p = xb2[tok * 100 + kk];
        xT16[kk][tok] = packf16(p.x, p.y);
    }
    __syncthreads();

    const unsigned* Wp = Wt16 + dir * 100 * G4;
    int j0 = tid, j1 = tid + 512;
    float acc0[32], acc1[32];
    #pragma unroll
    for (int t = 0; t < 32; t++) { acc0[t] = 0.0f; acc1[t] = 0.0f; }

    for (int kk = 0; kk < 100; kk++) {
        unsigned w0 = Wp[kk * G4 + j0];
        unsigned w1 = Wp[kk * G4 + j1];
        #pragma unroll
        for (int m = 0; m < 8; m++) {
            uint4 xx = *(const uint4*)&xT16[kk][4 * m];
            acc0[4 * m + 0] = dot2acc(xx.x, w0, acc0[4 * m + 0]);
            acc0[4 * m + 1] = dot2acc(xx.y, w0, acc0[4 * m + 1]);
            acc0[4 * m + 2] = dot2acc(xx.z, w0, acc0[4 * m + 2]);
            acc0[4 * m + 3] = dot2acc(xx.w, w0, acc0[4 * m + 3]);
            acc1[4 * m + 0] = dot2acc(xx.x, w1, acc1[4 * m + 0]);
            acc1[4 * m + 1] = dot2acc(xx.y, w1, acc1[4 * m + 1]);
            acc1[4 * m + 2] = dot2acc(xx.z, w1, acc1[4 * m + 2]);
            acc1[4 * m + 3] = dot2acc(xx.w, w1, acc1[4 * m + 3]);
        }
    }

    float bs0, bs1;
    if (dir) { bs0 = bihr[j0] + bhhr[j0]; bs1 = bihr[j1] + bhhr[j1]; }
    else     { bs0 = bihl[j0] + bhhl[j0]; bs1 = bihl[j1] + bhhl[j1]; }

    float* gbase = gx + ((dir * BB + b) * SS + s0) * G4;
    #pragma unroll
    for (int t = 0; t < 32; t++) {
        gbase[t * G4 + j0] = acc0[t] + bs0;
        gbase[t * G4 + j1] = acc1[t] + bs1;
    }
}

// ---------------- K3: LSTM, 2 CUs per sequence (K-split), 256 blocks x 256 thr ----
// Block bid: seq = bid&127 (dir,b), kh = bid>>7 = K-half owner.
// Thread t = h-col c; computes rows {c,256+c,512+c,768+c} over k in [kh*128,+128).
// All 256 weight-u32 in regs: 48 uint4 pinned VGPR + 16 uint4 pinned AGPR.
// h half (128 f16) lives in LDS (broadcast reads). Block kh finalizes h-cols
// [kh*128,+128) == exactly the h its own dots need -> NO h exchange; only 512
// f32 partials/step cross CUs via L2 mail + flag (agent-scope atomics).
__global__ void
__attribute__((amdgpu_flat_work_group_size(256, 256), amdgpu_waves_per_eu(1, 1)))
k_lstm(const _Float16* __restrict__ wpack, const float* __restrict__ gx,
       float* __restrict__ out, float* __restrict__ mail, unsigned* __restrict__ flags) {
    __shared__ unsigned hlds[2][64];   // [parity][own h-half as f16 pairs]

    int t = threadIdx.x;
    int bid = blockIdx.x;
    int seq = bid & 127, kh = bid >> 7;
    int dir = seq >> 6, b = seq & 63;
    bool keeper = ((t >> 7) == kh);          // wave-uniform role
    int tloc = t - kh * 128;                 // keeper's local col / h slot
    int ownf = (seq * 2 + kh) * 32;
    int sibf = (seq * 2 + (1 - kh)) * 32;

    // ---- weight load: 64 uint4, coalesced from chunk-major pack ----
    const uint4* wp = reinterpret_cast<const uint4*>(wpack) + (size_t)dir * 32 * G4;
    uint4 w0[16], w1[16], w2[16], w3[16];
    #pragma unroll
    for (int i = 0; i < 16; i++) {
        w0[i] = wp[(kh * 16 + i) * G4 + 0 * 256 + t];
        w1[i] = wp[(kh * 16 + i) * G4 + 1 * 256 + t];
        w2[i] = wp[(kh * 16 + i) * G4 + 2 * 256 + t];
        w3[i] = wp[(kh * 16 + i) * G4 + 3 * 256 + t];
    }
    // pin: 12 chunks/gate in arch VGPRs, 4 chunks/gate in AGPRs (unified file)
    #pragma unroll
    for (int i = 0; i < 12; i++) {
        asm volatile("" : "+v"(w0[i].x), "+v"(w0[i].y), "+v"(w0[i].z), "+v"(w0[i].w));
        asm volatile("" : "+v"(w1[i].x), "+v"(w1[i].y), "+v"(w1[i].z), "+v"(w1[i].w));
        asm volatile("" : "+v"(w2[i].x), "+v"(w2[i].y), "+v"(w2[i].z), "+v"(w2[i].w));
        asm volatile("" : "+v"(w3[i].x), "+v"(w3[i].y), "+v"(w3[i].z), "+v"(w3[i].w));
    }
    #pragma unroll
    for (int i = 12; i < 16; i++) {
        asm volatile("" : "+a"(w0[i].x), "+a"(w0[i].y), "+a"(w0[i].z), "+a"(w0[i].w));
        asm volatile("" : "+a"(w1[i].x), "+a"(w1[i].y), "+a"(w1[i].z), "+a"(w1[i].w));
        asm volatile("" : "+a"(w2[i].x), "+a"(w2[i].y), "+a"(w2[i].z), "+a"(w2[i].w));
        asm volatile("" : "+a"(w3[i].x), "+a"(w3[i].y), "+a"(w3[i].z), "+a"(w3[i].w));
    }

    const float* gxp = gx + (size_t)(dir * BB + b) * SS * G4;

    if (t < 128) reinterpret_cast<unsigned*>(hlds)[t] = 0u;
    float cst = 0.0f;
    __syncthreads();

    int ts = dir ? (SS - 1) : 0;
    int dstep = dir ? -1 : 1;
    float gxc[4] = {0.f, 0.f, 0.f, 0.f};
    if (keeper) {
        const float* g0p = gxp + (size_t)ts * G4;
        #pragma unroll
        for (int g = 0; g < 4; g++) gxc[g] = g0p[g * 256 + t];
    }

    for (int s = 0; s < SS; s++) {
        int par = s & 1;

        // dots over own k-half; h-chunk reads are wave-uniform (LDS broadcast)
        const uint4* hl = reinterpret_cast<const uint4*>(hlds[par]);
        float a0 = 0.f, a1 = 0.f, a2 = 0.f, a3 = 0.f;
        #pragma unroll
        for (int i = 0; i < 16; i++) {
            uint4 hh = hl[i];
            a0 = dot2acc(hh.x, w0[i].x, a0); a0 = dot2acc(hh.y, w0[i].y, a0);
            a0 = dot2acc(hh.z, w0[i].z, a0); a0 = dot2acc(hh.w, w0[i].w, a0);
            a1 = dot2acc(hh.x, w1[i].x, a1); a1 = dot2acc(hh.y, w1[i].y, a1);
            a1 = dot2acc(hh.z, w1[i].z, a1); a1 = dot2acc(hh.w, w1[i].w, a1);
            a2 = dot2acc(hh.x, w2[i].x, a2); a2 = dot2acc(hh.y, w2[i].y, a2);
            a2 = dot2acc(hh.z, w2[i].z, a2); a2 = dot2acc(hh.w, w2[i].w, a2);
            a3 = dot2acc(hh.x, w3[i].x, a3); a3 = dot2acc(hh.y, w3[i].y, a3);
            a3 = dot2acc(hh.z, w3[i].z, a3); a3 = dot2acc(hh.w, w3[i].w, a3);
        }

        // keeper: prefetch next step's gx while exchange happens
        float ngx[4] = {0.f, 0.f, 0.f, 0.f};
        if (keeper && s < SS - 1) {
            const float* gn = gxp + (size_t)(ts + dstep) * G4;
            #pragma unroll
            for (int g = 0; g < 4; g++) ngx[g] = gn[g * 256 + t];
        }

        if (!keeper) {
            // export partials for sibling-finalized col t
            int mi = ((seq * 2 + (1 - kh)) * 2 + par) * 128 + (t - (1 - kh) * 128);
            reinterpret_cast<float4*>(mail)[mi] = make_float4(a0, a1, a2, a3);
        }
        __syncthreads();   // exporters' stores drained (vmcnt) before flag

        if (t == 0) {
            __hip_atomic_store(&flags[ownf], (unsigned)(s + 1),
                               __ATOMIC_RELEASE, __HIP_MEMORY_SCOPE_AGENT);
            while (__hip_atomic_load(&flags[sibf], __ATOMIC_RELAXED,
                                     __HIP_MEMORY_SCOPE_AGENT) < (unsigned)(s + 1)) {
                __builtin_amdgcn_s_sleep(1);
            }
            // acquire: L1-invalidating load so the whole CU sees sibling's mail
            (void)__hip_atomic_load(&flags[sibf], __ATOMIC_ACQUIRE,
                                    __HIP_MEMORY_SCOPE_AGENT);
        }
        __syncthreads();

        if (keeper) {
            int mi = ((seq * 2 + kh) * 2 + par) * 128 + tloc;
            const unsigned* mu = reinterpret_cast<const unsigned*>(mail) + (size_t)mi * 4;
            float p0 = __uint_as_float(__hip_atomic_load(mu + 0, __ATOMIC_RELAXED,
                                                         __HIP_MEMORY_SCOPE_AGENT));
            float p1 = __uint_as_float(__hip_atomic_load(mu + 1, __ATOMIC_RELAXED,
                                                         __HIP_MEMORY_SCOPE_AGENT));
            float p2 = __uint_as_float(__hip_atomic_load(mu + 2, __ATOMIC_RELAXED,
                                                         __HIP_MEMORY_SCOPE_AGENT));
            float p3 = __uint_as_float(__hip_atomic_load(mu + 3, __ATOMIC_RELAXED,
                                                         __HIP_MEMORY_SCOPE_AGENT));
            float ig = sigm_f(a0 + p0 + gxc[0]);
            float fg = sigm_f(a1 + p1 + gxc[1]);
            float gg = tanh_f(a2 + p2 + gxc[2]);
            float og = sigm_f(a3 + p3 + gxc[3]);
            cst = fg * cst + ig * gg;
            float hv = og * tanh_f(cst);
            out[((size_t)b * SS + ts) * (2 * HID) + dir * HID + t] = hv;
            reinterpret_cast<unsigned short*>(hlds[par ^ 1])[tloc] =
                __builtin_bit_cast(unsigned short, (_Float16)hv);
            #pragma unroll
            for (int g = 0; g < 4; g++) gxc[g] = ngx[g];
        }
        __syncthreads();

        ts += dstep;
    }
}

extern "C" void kernel_launch(void* const* d_in, const int* in_sizes, int n_in,
                              void* d_out, int out_size, void* d_ws, size_t ws_size,
                              hipStream_t stream) {
    const int* char_features      = (const int*)d_in[0];
    const int* bichar_left        = (const int*)d_in[1];
    const int* bichar_right       = (const int*)d_in[2];
    const int* static_char        = (const int*)d_in[3];
    const int* static_bichar_left = (const int*)d_in[4];
    const int* static_bichar_right= (const int*)d_in[5];
    const float* char_emb         = (const float*)d_in[6];
    const float* bichar_emb       = (const float*)d_in[7];
    const float* static_char_emb  = (const float*)d_in[8];
    const float* static_bichar_emb= (const float*)d_in[9];
    const float* W_lin            = (const float*)d_in[10];
    const float* b_lin            = (const float*)d_in[11];
    const float* Wih_l            = (const float*)d_in[12];
    const float* Whh_l            = (const float*)d_in[13];
    const float* bih_l            = (const float*)d_in[14];
    const float* bhh_l            = (const float*)d_in[15];
    const float* Wih_r            = (const float*)d_in[16];
    const float* Whh_r            = (const float*)d_in[17];
    const float* bih_r            = (const float*)d_in[18];
    const float* bhh_r            = (const float*)d_in[19];

    float* ws    = (float*)d_ws;
    float* wtlin = ws + OFF_WTLIN;
    unsigned* wtih16 = (unsigned*)(ws + OFF_WTIH);
    _Float16* wpack = (_Float16*)(ws + OFF_WPACK);
    float* xbuf  = ws + OFF_X;
    float* gxbuf = ws + OFF_GX;
    float* mail  = ws + OFF_MAIL;
    unsigned* flags = (unsigned*)(ws + OFF_FLAG);
    float* out   = (float*)d_out;

    kt_wlin<<<(D_RNN * D_IN + 255) / 256, 256, 0, stream>>>(W_lin, wtlin);
    kt_wih16<<<(2 * G4 * 100 + 255) / 256, 256, 0, stream>>>(Wih_l, Wih_r, wtih16);
    kt_wpack<<<(2 * G4 * HID + 255) / 256, 256, 0, stream>>>(Whh_l, Whh_r, wpack);

    k_embed_linear<<<(BB * SS) / 16, 512, 0, stream>>>(
        char_features, bichar_left, bichar_right, static_char,
        static_bichar_left, static_bichar_right,
        char_emb, bichar_emb, static_char_emb, static_bichar_emb,
        wtlin, b_lin, xbuf);

    k_gatex<<<(2 * BB * SS) / 32, 512, 0, stream>>>(
        xbuf, wtih16, bih_l, bhh_l, bih_r, bhh_r, gxbuf);

    kf_reset<<<8, 1024, 0, stream>>>(flags);

    k_lstm<<<256, 256, 0, stream>>>(wpack, gxbuf, out, mail, flags);
}

// Round 8
// 924.089 us; speedup vs baseline: 2.3325x; 2.3325x over previous
//
#include <hip/hip_runtime.h>
#include <math.h>

#define BB 64
#define SS 256
#define D_IN 400
#define D_RNN 200
#define HID 256
#define G4 1024   // 4*HID

// workspace layout (float offsets)
#define OFF_WTLIN 0                            // [400][200] f32
#define OFF_WTIH  (OFF_WTLIN + 400*200)        // [2][100][1024] u32 (f16 pairs)
#define OFF_WPACK (OFF_WTIH + 2*200*1024)      // [2][8 chunk][1024 row][4 ks] uint4 of 8 f16
#define OFF_X     (OFF_WPACK + 2*1024*256/2)   // [2][64][256][200] f32
#define OFF_GX    (OFF_X + 2*64*256*200)       // [2][64][256][1024] f32

typedef _Float16 half2_t __attribute__((ext_vector_type(2)));

__device__ __forceinline__ half2_t u2h(unsigned u) {
    union { unsigned u; half2_t h; } x; x.u = u; return x.h;
}

__device__ __forceinline__ float dot2acc(unsigned hu, unsigned wu, float acc) {
#if __has_builtin(__builtin_amdgcn_fdot2)
    return __builtin_amdgcn_fdot2(u2h(hu), u2h(wu), acc, false);
#else
    half2_t h = u2h(hu), w = u2h(wu);
    acc = fmaf((float)h.x, (float)w.x, acc);
    acc = fmaf((float)h.y, (float)w.y, acc);
    return acc;
#endif
}

__device__ __forceinline__ unsigned packf16(float a, float b) {
    union { _Float16 h[2]; unsigned u; } x;
    x.h[0] = (_Float16)a; x.h[1] = (_Float16)b;
    return x.u;
}

__device__ __forceinline__ float sigm_f(float x) {
    return 1.0f / (1.0f + __expf(-x));
}
__device__ __forceinline__ float tanh_f(float x) {
    return 2.0f / (1.0f + __expf(-2.0f * x)) - 1.0f;
}

// quad (4-lane) butterfly sum via DPP: lanes t, t^1, t^2 hold ks 0..3 of same rg
__device__ __forceinline__ float quad_sum(float v) {
    int i = __float_as_int(v);
    v += __int_as_float(__builtin_amdgcn_update_dpp(0, i, 0xB1, 0xF, 0xF, true));
    i = __float_as_int(v);
    v += __int_as_float(__builtin_amdgcn_update_dpp(0, i, 0x4E, 0xF, 0xF, true));
    return v;
}

// ---------------- transposes / packs ----------------
__global__ void kt_wlin(const float* __restrict__ W, float* __restrict__ Wt) {
    int id = blockIdx.x * 256 + threadIdx.x;
    if (id >= D_RNN * D_IN) return;
    int j = id / D_IN, k = id % D_IN;
    Wt[k * D_RNN + j] = W[id];
}

// Wih f32 [1024][200] -> f16-pair pack
__global__ void kt_wih16(const float* __restrict__ Wl, const float* __restrict__ Wr,
                         unsigned* __restrict__ Wt16) {
    int id = blockIdx.x * 256 + threadIdx.x;
    if (id >= 2 * G4 * 100) return;
    int dir = id / (G4 * 100);
    int rem = id % (G4 * 100);
    int j = rem / 100, kk = rem % 100;
    const float* src = dir ? Wr : Wl;
    Wt16[(dir * 100 + kk) * G4 + j] = packf16(src[j * D_RNN + 2 * kk],
                                              src[j * D_RNN + 2 * kk + 1]);
}

// Whh f32 [1024][256] -> wp3[dir][i<8][row][ks<4] = uint4 of 8 f16 (k = ks*64+i*8 ..+8)
__global__ void kt_wpack3(const float* __restrict__ Wl, const float* __restrict__ Wr,
                          uint4* __restrict__ Wp) {
    int id = blockIdx.x * 256 + threadIdx.x;     // uint4 id, total 65536
    if (id >= 2 * 8 * 1024 * 4) return;
    int ks = id & 3;
    int r = (id >> 2) & 1023;
    int i = (id >> 12) & 7;
    int dir = id >> 15;
    const float* src = dir ? Wr : Wl;
    int k0 = ks * 64 + i * 8;
    union { unsigned short h[8]; uint4 u; } o;
    #pragma unroll
    for (int q = 0; q < 8; q++)
        o.h[q] = __builtin_bit_cast(unsigned short, (_Float16)src[r * HID + k0 + q]);
    Wp[id] = o.u;
}

// ---------------- K1: embeddings + concat + linear + tanh ----------------
__launch_bounds__(512)
__global__ void k_embed_linear(const int* __restrict__ ci, const int* __restrict__ bli,
                               const int* __restrict__ bri, const int* __restrict__ sci,
                               const int* __restrict__ sbli, const int* __restrict__ sbri,
                               const float* __restrict__ ce, const float* __restrict__ be,
                               const float* __restrict__ sce, const float* __restrict__ sbe,
                               const float* __restrict__ Wt, const float* __restrict__ blin,
                               float* __restrict__ xout) {
    __shared__ __align__(16) float vec[16][2][D_IN];
    __shared__ int idx[16][6];
    int tid = threadIdx.x;
    int g0 = blockIdx.x * 16;

    if (tid < 96) {
        int tt = tid / 6, w = tid % 6;
        int g = g0 + tt;
        const int* arr = (w == 0) ? ci : (w == 1) ? sci : (w == 2) ? bli
                         : (w == 3) ? bri : (w == 4) ? sbli : sbri;
        idx[tt][w] = arr[g];
    }
    __syncthreads();

    for (int v = tid; v < 16 * D_IN; v += 512) {
        int tt = v / D_IN, p = v % D_IN;
        float lv, rv;
        if (p < 100)      { float e = ce[idx[tt][0] * 100 + p];          lv = rv = e; }
        else if (p < 200) { float e = sce[idx[tt][1] * 100 + (p - 100)]; lv = rv = e; }
        else if (p < 300) { int q = p - 200;
                            lv = be[idx[tt][2] * 100 + q];
                            rv = be[idx[tt][3] * 100 + q]; }
        else              { int q = p - 300;
                            lv = sbe[idx[tt][4] * 100 + q];
                            rv = sbe[idx[tt][5] * 100 + q]; }
        vec[tt][0][p] = lv;
        vec[tt][1][p] = rv;
    }
    __syncthreads();

    if (tid < 400) {
        int side = tid / 200, j = tid % 200;
        float acc[16];
        #pragma unroll
        for (int t = 0; t < 16; t++) acc[t] = 0.0f;

        for (int k4 = 0; k4 < D_IN / 4; k4++) {
            float w0 = Wt[(4 * k4 + 0) * D_RNN + j];
            float w1 = Wt[(4 * k4 + 1) * D_RNN + j];
            float w2 = Wt[(4 * k4 + 2) * D_RNN + j];
            float w3 = Wt[(4 * k4 + 3) * D_RNN + j];
            #pragma unroll
            for (int t = 0; t < 16; t++) {
                float4 xv = *(const float4*)&vec[t][side][4 * k4];
                acc[t] += xv.x * w0 + xv.y * w1 + xv.z * w2 + xv.w * w3;
            }
        }
        float bias = blin[j];
        #pragma unroll
        for (int t = 0; t < 16; t++) {
            int g = g0 + t;
            int b = g >> 8, s = g & 255;
            xout[((side * BB + b) * SS + s) * D_RNN + j] = tanh_f(acc[t] + bias);
        }
    }
}

// ---------------- K2: gate-x GEMM via f16 dot2 ----------------
__launch_bounds__(512)
__global__ void k_gatex(const float* __restrict__ x, const unsigned* __restrict__ Wt16,
                        const float* __restrict__ bihl, const float* __restrict__ bhhl,
                        const float* __restrict__ bihr, const float* __restrict__ bhhr,
                        float* __restrict__ gx) {
    __shared__ __align__(16) unsigned xT16[100][40];
    int tid = threadIdx.x;
    int id = blockIdx.x;
    int dir = id >> 9;
    int rem = id & 511;
    int b = rem >> 3;
    int s0 = (rem & 7) * 32;

    const float2* xb2 = reinterpret_cast<const float2*>(
        x + ((dir * BB + b) * SS + s0) * D_RNN);
    for (int v = tid; v < 32 * 100; v += 512) {
        int tok = v / 100, kk = v % 100;
        float2 p = xb2[tok * 100 + kk];
        xT16[kk][tok] = packf16(p.x, p.y);
    }
    __syncthreads();

    const unsigned* Wp = Wt16 + dir * 100 * G4;
    int j0 = tid, j1 = tid + 512;
    float acc0[32], acc1[32];
    #pragma unroll
    for (int t = 0; t < 32; t++) { acc0[t] = 0.0f; acc1[t] = 0.0f; }

    for (int kk = 0; kk < 100; kk++) {
        unsigned w0 = Wp[kk * G4 + j0];
        unsigned w1 = Wp[kk * G4 + j1];
        #pragma unroll
        for (int m = 0; m < 8; m++) {
            uint4 xx = *(const uint4*)&xT16[kk][4 * m];
            acc0[4 * m + 0] = dot2acc(xx.x, w0, acc0[4 * m + 0]);
            acc0[4 * m + 1] = dot2acc(xx.y, w0, acc0[4 * m + 1]);
            acc0[4 * m + 2] = dot2acc(xx.z, w0, acc0[4 * m + 2]);
            acc0[4 * m + 3] = dot2acc(xx.w, w0, acc0[4 * m + 3]);
            acc1[4 * m + 0] = dot2acc(xx.x, w1, acc1[4 * m + 0]);
            acc1[4 * m + 1] = dot2acc(xx.y, w1, acc1[4 * m + 1]);
            acc1[4 * m + 2] = dot2acc(xx.z, w1, acc1[4 * m + 2]);
            acc1[4 * m + 3] = dot2acc(xx.w, w1, acc1[4 * m + 3]);
        }
    }

    float bs0, bs1;
    if (dir) { bs0 = bihr[j0] + bhhr[j0]; bs1 = bihr[j1] + bhhr[j1]; }
    else     { bs0 = bihl[j0] + bhhl[j0]; bs1 = bihl[j1] + bhhl[j1]; }

    float* gbase = gx + ((dir * BB + b) * SS + s0) * G4;
    #pragma unroll
    for (int t = 0; t < 32; t++) {
        gbase[t * G4 + j0] = acc0[t] + bs0;
        gbase[t * G4 + j1] = acc1[t] + bs1;
    }
}

// ---------------- K3: LSTM, ONE block per (dir,b). 256 thr, 1 wave/SIMD.
// Thread (rg=t>>2, ks=t&3): 16 gate rows [rg*16,+16) over k in [ks*64,+64).
// Weight chunks (uint4 = 8 f16): i=0..3 pinned AGPR (64 uint4 = 256 a),
// i=4..6 pinned VGPR (48 uint4 = 192 v), i=7 from LDS (xor-swizzled).
// h k-sliced: 8 uint4 from padded LDS (conflict-free). Cross-ks reduce via
// DPP quad butterfly (VALU). Thread t also finalizes h-column t.
__global__ void
__attribute__((amdgpu_flat_work_group_size(256, 256), amdgpu_waves_per_eu(1, 1)))
k_lstm(const uint4* __restrict__ wp3, const float* __restrict__ gx,
       float* __restrict__ out) {
    __shared__ __align__(16) uint4 wl[1024 * 4];      // 65536 B, [row*4 + (ks^(rg&3))]
    __shared__ __align__(16) float gates[64 * 20];    // 5120 B, [rg*20 + j], pad 4
    __shared__ __align__(16) unsigned hbuf[4 * 36];   // 576 B, [ks*36 + i], pad 4

    int t = threadIdx.x;
    int rg = t >> 2, ks = t & 3;
    int bid = blockIdx.x;
    int dir = bid >> 6, b = bid & 63;

    const uint4* wp = wp3 + (size_t)dir * 8 * 1024 * 4;
    int row0 = rg * 16;

    // ---- one-time weight loads ----
    uint4 wa[4][16], wv[3][16];
    #pragma unroll
    for (int i = 0; i < 4; i++)
        #pragma unroll
        for (int j = 0; j < 16; j++)
            wa[i][j] = wp[(i * 1024 + row0 + j) * 4 + ks];
    #pragma unroll
    for (int i = 0; i < 3; i++)
        #pragma unroll
        for (int j = 0; j < 16; j++)
            wv[i][j] = wp[((i + 4) * 1024 + row0 + j) * 4 + ks];
    // pin: i0..3 -> AGPR, i4..6 -> VGPR (prevents demotion/sinking)
    #pragma unroll
    for (int i = 0; i < 4; i++)
        #pragma unroll
        for (int j = 0; j < 16; j++)
            asm volatile("" : "+a"(wa[i][j].x), "+a"(wa[i][j].y),
                              "+a"(wa[i][j].z), "+a"(wa[i][j].w));
    #pragma unroll
    for (int i = 0; i < 3; i++)
        #pragma unroll
        for (int j = 0; j < 16; j++)
            asm volatile("" : "+v"(wv[i][j].x), "+v"(wv[i][j].y),
                              "+v"(wv[i][j].z), "+v"(wv[i][j].w));
    // stage chunk 7 into LDS (xor-swizzled by rg to break 16-way conflicts)
    int kssw = ks ^ (rg & 3);
    #pragma unroll
    for (int j = 0; j < 16; j++)
        wl[(row0 + j) * 4 + kssw] = wp[(7 * 1024 + row0 + j) * 4 + ks];

    if (t < 144) hbuf[t] = 0u;

    const float* gxp = gx + (size_t)(dir * BB + b) * SS * G4;
    float cst = 0.0f;
    int ts = dir ? (SS - 1) : 0;
    int dstep = dir ? -1 : 1;
    float gxc[4];
    #pragma unroll
    for (int g = 0; g < 4; g++) gxc[g] = gxp[(size_t)ts * G4 + g * 256 + t];
    __syncthreads();

    int hb = ks * 36;                    // u32 index of own h-slice
    int wlb = row0 * 4 + kssw;           // uint4 index of own chunk-7 rows
    int g0i = (0 * 16 + (t >> 4)) * 20 + (t & 15);   // gates read idx, gate i
    int g1i = (1 * 16 + (t >> 4)) * 20 + (t & 15);
    int g2i = (2 * 16 + (t >> 4)) * 20 + (t & 15);
    int g3i = (3 * 16 + (t >> 4)) * 20 + (t & 15);
    int hwi = ((t >> 6) * 36 + ((t & 63) >> 1)) * 2 + (t & 1);  // h write (short idx)
    unsigned short* hs = reinterpret_cast<unsigned short*>(hbuf);
    float* outp = out + (size_t)b * SS * (2 * HID) + dir * HID + t;

    for (int s = 0; s < SS; s++) {
        // ---- h-slice loads (8 uint4, conflict-free via pad) ----
        uint4 h0 = *(const uint4*)&hbuf[hb + 0];
        uint4 h1 = *(const uint4*)&hbuf[hb + 4];
        uint4 h2 = *(const uint4*)&hbuf[hb + 8];
        uint4 h3 = *(const uint4*)&hbuf[hb + 12];

        float acc[16];
        #pragma unroll
        for (int j = 0; j < 16; j++) acc[j] = 0.0f;

#define DOT4(A, H, W4) \
        A = dot2acc((H).x, (W4).x, A); A = dot2acc((H).y, (W4).y, A); \
        A = dot2acc((H).z, (W4).z, A); A = dot2acc((H).w, (W4).w, A);

        #pragma unroll
        for (int j = 0; j < 16; j++) { DOT4(acc[j], h0, wa[0][j]); }
        uint4 h4 = *(const uint4*)&hbuf[hb + 16];
        uint4 h5 = *(const uint4*)&hbuf[hb + 20];
        #pragma unroll
        for (int j = 0; j < 16; j++) { DOT4(acc[j], h1, wa[1][j]); }
        uint4 h6 = *(const uint4*)&hbuf[hb + 24];
        uint4 h7 = *(const uint4*)&hbuf[hb + 28];
        #pragma unroll
        for (int j = 0; j < 16; j++) { DOT4(acc[j], h2, wa[2][j]); }
        #pragma unroll
        for (int j = 0; j < 16; j++) { DOT4(acc[j], h3, wa[3][j]); }
        #pragma unroll
        for (int j = 0; j < 16; j++) { DOT4(acc[j], h4, wv[0][j]); }
        #pragma unroll
        for (int j = 0; j < 16; j++) { DOT4(acc[j], h5, wv[1][j]); }
        #pragma unroll
        for (int j = 0; j < 16; j++) { DOT4(acc[j], h6, wv[2][j]); }

        // ---- chunk 7 from LDS, 8-deep pipelined ----
        {
            uint4 q0 = wl[wlb + 0],  q1 = wl[wlb + 4];
            uint4 q2 = wl[wlb + 8],  q3 = wl[wlb + 12];
            uint4 r0 = wl[wlb + 16], r1 = wl[wlb + 20];
            uint4 r2 = wl[wlb + 24], r3 = wl[wlb + 28];
            DOT4(acc[0], h7, q0); DOT4(acc[1], h7, q1);
            DOT4(acc[2], h7, q2); DOT4(acc[3], h7, q3);
            q0 = wl[wlb + 32]; q1 = wl[wlb + 36]; q2 = wl[wlb + 40]; q3 = wl[wlb + 44];
            DOT4(acc[4], h7, r0); DOT4(acc[5], h7, r1);
            DOT4(acc[6], h7, r2); DOT4(acc[7], h7, r3);
            r0 = wl[wlb + 48]; r1 = wl[wlb + 52]; r2 = wl[wlb + 56]; r3 = wl[wlb + 60];
            DOT4(acc[8], h7, q0);  DOT4(acc[9], h7, q1);
            DOT4(acc[10], h7, q2); DOT4(acc[11], h7, q3);
            DOT4(acc[12], h7, r0); DOT4(acc[13], h7, r1);
            DOT4(acc[14], h7, r2); DOT4(acc[15], h7, r3);
        }
#undef DOT4

        // ---- cross-ks reduction: DPP quad butterfly (lanes = 4*rg + ks) ----
        #pragma unroll
        for (int j = 0; j < 16; j++) acc[j] = quad_sum(acc[j]);

        if (ks == 0) {
            *(float4*)&gates[rg * 20 + 0]  = make_float4(acc[0], acc[1], acc[2], acc[3]);
            *(float4*)&gates[rg * 20 + 4]  = make_float4(acc[4], acc[5], acc[6], acc[7]);
            *(float4*)&gates[rg * 20 + 8]  = make_float4(acc[8], acc[9], acc[10], acc[11]);
            *(float4*)&gates[rg * 20 + 12] = make_float4(acc[12], acc[13], acc[14], acc[15]);
        }
        __syncthreads();

        // ---- finalize column t ----
        {
            float ig = sigm_f(gates[g0i] + gxc[0]);
            float fg = sigm_f(gates[g1i] + gxc[1]);
            float gg = tanh_f(gates[g2i] + gxc[2]);
            float og = sigm_f(gates[g3i] + gxc[3]);
            cst = fg * cst + ig * gg;
            float hv = og * tanh_f(cst);
            outp[(size_t)ts * (2 * HID)] = hv;
            hs[hwi] = __builtin_bit_cast(unsigned short, (_Float16)hv);
            // prefetch next step's gx (hidden across the barrier + next dots)
            int tn = (s < SS - 1) ? (ts + dstep) : ts;
            #pragma unroll
            for (int g = 0; g < 4; g++) gxc[g] = gxp[(size_t)tn * G4 + g * 256 + t];
        }
        __syncthreads();

        ts += dstep;
    }
}

extern "C" void kernel_launch(void* const* d_in, const int* in_sizes, int n_in,
                              void* d_out, int out_size, void* d_ws, size_t ws_size,
                              hipStream_t stream) {
    const int* char_features      = (const int*)d_in[0];
    const int* bichar_left        = (const int*)d_in[1];
    const int* bichar_right       = (const int*)d_in[2];
    const int* static_char        = (const int*)d_in[3];
    const int* static_bichar_left = (const int*)d_in[4];
    const int* static_bichar_right= (const int*)d_in[5];
    const float* char_emb         = (const float*)d_in[6];
    const float* bichar_emb       = (const float*)d_in[7];
    const float* static_char_emb  = (const float*)d_in[8];
    const float* static_bichar_emb= (const float*)d_in[9];
    const float* W_lin            = (const float*)d_in[10];
    const float* b_lin            = (const float*)d_in[11];
    const float* Wih_l            = (const float*)d_in[12];
    const float* Whh_l            = (const float*)d_in[13];
    const float* bih_l            = (const float*)d_in[14];
    const float* bhh_l            = (const float*)d_in[15];
    const float* Wih_r            = (const float*)d_in[16];
    const float* Whh_r            = (const float*)d_in[17];
    const float* bih_r            = (const float*)d_in[18];
    const float* bhh_r            = (const float*)d_in[19];

    float* ws    = (float*)d_ws;
    float* wtlin = ws + OFF_WTLIN;
    unsigned* wtih16 = (unsigned*)(ws + OFF_WTIH);
    uint4* wp3   = (uint4*)(ws + OFF_WPACK);
    float* xbuf  = ws + OFF_X;
    float* gxbuf = ws + OFF_GX;
    float* out   = (float*)d_out;

    kt_wlin<<<(D_RNN * D_IN + 255) / 256, 256, 0, stream>>>(W_lin, wtlin);
    kt_wih16<<<(2 * G4 * 100 + 255) / 256, 256, 0, stream>>>(Wih_l, Wih_r, wtih16);
    kt_wpack3<<<(2 * 8 * 1024 * 4) / 256, 256, 0, stream>>>(Whh_l, Whh_r, wp3);

    k_embed_linear<<<(BB * SS) / 16, 512, 0, stream>>>(
        char_features, bichar_left, bichar_right, static_char,
        static_bichar_left, static_bichar_right,
        char_emb, bichar_emb, static_char_emb, static_bichar_emb,
        wtlin, b_lin, xbuf);

    k_gatex<<<(2 * BB * SS) / 32, 512, 0, stream>>>(
        xbuf, wtih16, bih_l, bhh_l, bih_r, bhh_r, gxbuf);

    k_lstm<<<2 * BB, 256, 0, stream>>>(wp3, gxbuf, out);
}